// Round 1
// baseline (39258.966 us; speedup 1.0000x reference)
//
#include <hip/hip_runtime.h>
#include <hip/hip_bf16.h>
#include <math.h>

#define Dn 12
#define Cc 768
#define NHh 12
#define HD 64
#define Gg 14
#define Nn_TOK 197
#define HID 3072
#define NC 1000
#define Bb 32

// ---------------- im2col: x (B,3,224,224) -> xp (B,196,768) ----------------
__global__ void im2col_kernel(const float* __restrict__ x, float* __restrict__ xp) {
    size_t idx = (size_t)blockIdx.x * 256 + threadIdx.x;
    const size_t total = (size_t)Bb * 196 * 768;
    if (idx >= total) return;
    int j = idx % 768;
    size_t t0 = idx / 768;
    int g = t0 % 196;
    int b = t0 / 196;
    int ch = j / 256, rem = j % 256, pr = rem / 16, pc = rem % 16;
    int gr = g / Gg, gc = g % Gg;
    int row = gr * 16 + pr, col = gc * 16 + pc;
    xp[idx] = x[(((size_t)b * 3 + ch) * 224 + row) * 224 + col];
}

// ---------------- assemble t = concat(cls, patches) + pos ----------------
__global__ void assemble_kernel(const float* __restrict__ pe, const float* __restrict__ cls,
                                const float* __restrict__ pos, float* __restrict__ t) {
    size_t idx = (size_t)blockIdx.x * 256 + threadIdx.x;
    const size_t total = (size_t)Bb * Nn_TOK * 768;
    if (idx >= total) return;
    int c = idx % 768;
    size_t r = idx / 768;
    int n = r % Nn_TOK, b = r / Nn_TOK;
    float v;
    if (n == 0) v = cls[c];
    else       v = pe[((size_t)b * 196 + (n - 1)) * 768 + c];
    t[idx] = v + pos[(size_t)n * 768 + c];
}

// ---------------- generic fp32 GEMM: out = A(MxK) @ B(KxN) [+bias][gelu][+residual] ----------------
#define BM 64
#define BN 64
#define BK 16
__global__ __launch_bounds__(256) void gemm_f32(
    const float* __restrict__ A, const float* __restrict__ B,
    float* __restrict__ out, const float* __restrict__ bias,
    const float* __restrict__ residual,
    int M, int N, int K, int transB, int do_gelu)
{
    __shared__ float As[BK][BM + 1];
    __shared__ float Bs[BK][BN + 1];
    int tid = threadIdx.x;
    int block_row = blockIdx.y * BM;
    int block_col = blockIdx.x * BN;
    int tx = tid % 16, ty = tid / 16;
    float acc[4][4] = {};
    for (int k0 = 0; k0 < K; k0 += BK) {
        for (int l = 0; l < 4; ++l) {
            int idx = tid + l * 256;
            int r = idx / BK, c = idx % BK;
            int gr = block_row + r, gc = k0 + c;
            As[c][r] = (gr < M && gc < K) ? A[(size_t)gr * K + gc] : 0.f;
        }
        for (int l = 0; l < 4; ++l) {
            int idx = tid + l * 256;
            int r = idx / BN, c = idx % BN;
            int gk = k0 + r, gn = block_col + c;
            float v = 0.f;
            if (gk < K && gn < N)
                v = transB ? B[(size_t)gn * K + gk] : B[(size_t)gk * N + gn];
            Bs[r][c] = v;
        }
        __syncthreads();
        for (int kk = 0; kk < BK; ++kk) {
            float a[4], bb[4];
            #pragma unroll
            for (int i = 0; i < 4; ++i) a[i] = As[kk][ty * 4 + i];
            #pragma unroll
            for (int j = 0; j < 4; ++j) bb[j] = Bs[kk][tx * 4 + j];
            #pragma unroll
            for (int i = 0; i < 4; ++i)
                #pragma unroll
                for (int j = 0; j < 4; ++j)
                    acc[i][j] += a[i] * bb[j];
        }
        __syncthreads();
    }
    for (int i = 0; i < 4; ++i) {
        int gr = block_row + ty * 4 + i;
        if (gr >= M) continue;
        for (int j = 0; j < 4; ++j) {
            int gn = block_col + tx * 4 + j;
            if (gn >= N) continue;
            float v = acc[i][j];
            if (bias) v += bias[gn];
            if (do_gelu) v = 0.5f * v * (1.f + erff(v * 0.70710678118654752f));
            if (residual) v += residual[(size_t)gr * N + gn];
            out[(size_t)gr * N + gn] = v;
        }
    }
}

// ---------------- LayerNorm: rows x 768 ----------------
__global__ __launch_bounds__(256) void ln_kernel(
    const float* __restrict__ in, float* __restrict__ out,
    const float* __restrict__ w, const float* __restrict__ b,
    long in_stride, long out_stride)
{
    int row = blockIdx.x;
    const float* xr = in + (size_t)row * in_stride;
    float* orow = out + (size_t)row * out_stride;
    int tid = threadIdx.x;
    float vals[3];
    float s = 0.f, s2 = 0.f;
    #pragma unroll
    for (int l = 0; l < 3; ++l) {
        float v = xr[tid + l * 256];
        vals[l] = v; s += v; s2 += v * v;
    }
    __shared__ float sh[256];
    __shared__ float stats[2];
    sh[tid] = s; __syncthreads();
    for (int o = 128; o > 0; o >>= 1) { if (tid < o) sh[tid] += sh[tid + o]; __syncthreads(); }
    if (tid == 0) stats[0] = sh[0];
    __syncthreads();
    sh[tid] = s2; __syncthreads();
    for (int o = 128; o > 0; o >>= 1) { if (tid < o) sh[tid] += sh[tid + o]; __syncthreads(); }
    if (tid == 0) stats[1] = sh[0];
    __syncthreads();
    float mean = stats[0] * (1.f / 768.f);
    float var = stats[1] * (1.f / 768.f) - mean * mean;
    float rstd = rsqrtf(var + 1e-5f);
    #pragma unroll
    for (int l = 0; l < 3; ++l) {
        int c = tid + l * 256;
        orow[c] = (vals[l] - mean) * rstd * w[c] + b[c];
    }
}

// ---------------- Attention: one block per (q-token, head, batch) ----------------
__global__ __launch_bounds__(256) void attn_kernel(
    const float* __restrict__ qkv, float* __restrict__ out)
{
    int n = blockIdx.x, h = blockIdx.y, b = blockIdx.z;
    int tid = threadIdx.x;
    __shared__ float qv[64];
    __shared__ float sprob[Nn_TOK];
    __shared__ float red[256];
    __shared__ float mval, lsum;
    const size_t base = (size_t)b * Nn_TOK * 2304;
    if (tid < 64) qv[tid] = qkv[base + (size_t)n * 2304 + h * 64 + tid];
    __syncthreads();
    float sc = -INFINITY;
    int k = tid;
    if (k < Nn_TOK) {
        bool valid;
        if (n == 0 || k == 0) valid = true;
        else {
            int rq = (n - 1) / Gg, cq = (n - 1) % Gg;
            int rk = (k - 1) / Gg, ck = (k - 1) % Gg;
            valid = (abs(rq - rk) <= 3) && (abs(cq - ck) <= 3);
        }
        if (valid) {
            const float* kr = qkv + base + (size_t)k * 2304 + 768 + h * 64;
            float d = 0.f;
            #pragma unroll
            for (int j = 0; j < 64; ++j) d += qv[j] * kr[j];
            sc = d * 0.125f;  // 1/sqrt(64)
        }
    }
    red[tid] = sc; __syncthreads();
    for (int o = 128; o > 0; o >>= 1) { if (tid < o) red[tid] = fmaxf(red[tid], red[tid + o]); __syncthreads(); }
    if (tid == 0) mval = red[0];
    __syncthreads();
    float e = (k < Nn_TOK) ? expf(sc - mval) : 0.f;  // exp(-inf - finite) = 0
    if (k < Nn_TOK) sprob[k] = e;
    red[tid] = e; __syncthreads();
    for (int o = 128; o > 0; o >>= 1) { if (tid < o) red[tid] += red[tid + o]; __syncthreads(); }
    if (tid == 0) lsum = red[0];
    __syncthreads();
    if (tid < 64) {
        float acc = 0.f;
        const float* vbase = qkv + base + 1536 + h * 64 + tid;
        for (int kk = 0; kk < Nn_TOK; ++kk)
            acc += sprob[kk] * vbase[(size_t)kk * 2304];
        out[((size_t)b * Nn_TOK + n) * 768 + h * 64 + tid] = acc / lsum;
    }
}

extern "C" void kernel_launch(void* const* d_in, const int* in_sizes, int n_in,
                              void* d_out, int out_size, void* d_ws, size_t ws_size,
                              hipStream_t stream) {
    const float* x        = (const float*)d_in[0];
    const float* patch_w  = (const float*)d_in[1];
    const float* patch_b  = (const float*)d_in[2];
    const float* cls_tok  = (const float*)d_in[3];
    const float* pos_emb  = (const float*)d_in[4];
    const float* ln1_w    = (const float*)d_in[5];
    const float* ln1_b    = (const float*)d_in[6];
    const float* qkv_w    = (const float*)d_in[7];
    const float* proj_w   = (const float*)d_in[8];
    const float* proj_b   = (const float*)d_in[9];
    const float* ln2_w    = (const float*)d_in[10];
    const float* ln2_b    = (const float*)d_in[11];
    const float* mlp_w1   = (const float*)d_in[12];
    const float* mlp_b1   = (const float*)d_in[13];
    const float* mlp_w2   = (const float*)d_in[14];
    const float* mlp_b2   = (const float*)d_in[15];
    const float* norm_w   = (const float*)d_in[16];
    const float* norm_b   = (const float*)d_in[17];
    const float* head_w   = (const float*)d_in[18];
    const float* head_b   = (const float*)d_in[19];
    float* out = (float*)d_out;

    const size_t M_tok = (size_t)Bb * Nn_TOK;               // 6304
    float* t    = (float*)d_ws;                             // 32*197*768
    float* buf1 = t + (size_t)Bb * Nn_TOK * 768;            // 32*197*768
    float* buf2 = buf1 + (size_t)Bb * Nn_TOK * 768;         // 32*197*3072

    // 1. im2col into buf2
    {
        size_t total = (size_t)Bb * 196 * 768;
        im2col_kernel<<<dim3((total + 255) / 256), dim3(256), 0, stream>>>(x, buf2);
    }
    // 2. patch embed GEMM: buf1 = buf2 (6272x768) @ patch_w^T (+patch_b)
    {
        int M = Bb * 196, N = Cc, K = 768;
        gemm_f32<<<dim3((N + BN - 1) / BN, (M + BM - 1) / BM), 256, 0, stream>>>(
            buf2, patch_w, buf1, patch_b, nullptr, M, N, K, 1, 0);
    }
    // 3. assemble t
    {
        size_t total = (size_t)Bb * Nn_TOK * 768;
        assemble_kernel<<<dim3((total + 255) / 256), 256, 0, stream>>>(buf1, cls_tok, pos_emb, t);
    }
    // 4. transformer layers
    for (int i = 0; i < Dn; ++i) {
        ln_kernel<<<dim3((int)M_tok), 256, 0, stream>>>(t, buf1, ln1_w + i * Cc, ln1_b + i * Cc, Cc, Cc);
        {
            int M = (int)M_tok, N = 3 * Cc, K = Cc;
            gemm_f32<<<dim3((N + BN - 1) / BN, (M + BM - 1) / BM), 256, 0, stream>>>(
                buf1, qkv_w + (size_t)i * Cc * 3 * Cc, buf2, nullptr, nullptr, M, N, K, 0, 0);
        }
        attn_kernel<<<dim3(Nn_TOK, NHh, Bb), 256, 0, stream>>>(buf2, buf1);
        {
            int M = (int)M_tok, N = Cc, K = Cc;
            gemm_f32<<<dim3((N + BN - 1) / BN, (M + BM - 1) / BM), 256, 0, stream>>>(
                buf1, proj_w + (size_t)i * Cc * Cc, t, proj_b + i * Cc, t, M, N, K, 0, 0);
        }
        ln_kernel<<<dim3((int)M_tok), 256, 0, stream>>>(t, buf1, ln2_w + i * Cc, ln2_b + i * Cc, Cc, Cc);
        {
            int M = (int)M_tok, N = HID, K = Cc;
            gemm_f32<<<dim3((N + BN - 1) / BN, (M + BM - 1) / BM), 256, 0, stream>>>(
                buf1, mlp_w1 + (size_t)i * Cc * HID, buf2, mlp_b1 + i * HID, nullptr, M, N, K, 0, 1);
        }
        {
            int M = (int)M_tok, N = Cc, K = HID;
            gemm_f32<<<dim3((N + BN - 1) / BN, (M + BM - 1) / BM), 256, 0, stream>>>(
                buf2, mlp_w2 + (size_t)i * HID * Cc, t, mlp_b2 + i * Cc, t, M, N, K, 0, 0);
        }
    }
    // 5. final LN on token 0 only -> buf1 (32x768 compact)
    ln_kernel<<<dim3(Bb), 256, 0, stream>>>(t, buf1, norm_w, norm_b, (long)Nn_TOK * Cc, Cc);
    // 6. head: out = buf1 @ head_w + head_b  (32 x 1000)
    {
        int M = Bb, N = NC, K = Cc;
        gemm_f32<<<dim3((N + BN - 1) / BN, (M + BM - 1) / BM), 256, 0, stream>>>(
            buf1, head_w, out, head_b, nullptr, M, N, K, 0, 0);
    }
}

// Round 2
// 9157.426 us; speedup vs baseline: 4.2871x; 4.2871x over previous
//
#include <hip/hip_runtime.h>
#include <hip/hip_bf16.h>
#include <math.h>

#define Dn 12
#define Cc 768
#define NHh 12
#define HD 64
#define Gg 14
#define Nn_TOK 197
#define HID 3072
#define NC 1000
#define Bb 32

typedef __attribute__((ext_vector_type(8))) short short8;
typedef __attribute__((ext_vector_type(4))) float f32x4;

__device__ __forceinline__ ushort f2b(float v) {
    union { float f; unsigned u; } x; x.f = v;
    unsigned r = x.u + 0x7fff + ((x.u >> 16) & 1);
    return (ushort)(r >> 16);
}
__device__ __forceinline__ float b2f(ushort v) {
    union { unsigned u; float f; } x; x.u = ((unsigned)v) << 16; return x.f;
}
__device__ __forceinline__ void gld16(const void* g, void* s) {
    __builtin_amdgcn_global_load_lds(
        (const __attribute__((address_space(1))) void*)g,
        (__attribute__((address_space(3))) void*)s, 16, 0, 0);
}

// ---------------- im2col: x (B,3,224,224) fp32 -> xp (B,196,768) bf16 ----------------
__global__ void im2col_kernel(const float* __restrict__ x, ushort* __restrict__ xp) {
    size_t idx = (size_t)blockIdx.x * 256 + threadIdx.x;
    const size_t total = (size_t)Bb * 196 * 768;
    if (idx >= total) return;
    int j = idx % 768;
    size_t t0 = idx / 768;
    int g = t0 % 196;
    int b = t0 / 196;
    int ch = j / 256, rem = j % 256, pr = rem / 16, pc = rem % 16;
    int gr = g / Gg, gc = g % Gg;
    int row = gr * 16 + pr, col = gc * 16 + pc;
    xp[idx] = f2b(x[(((size_t)b * 3 + ch) * 224 + row) * 224 + col]);
}

// ---------------- assemble t = concat(cls, patches) + pos (fp32) ----------------
__global__ void assemble_kernel(const float* __restrict__ pe, const float* __restrict__ cls,
                                const float* __restrict__ pos, float* __restrict__ t) {
    size_t idx = (size_t)blockIdx.x * 256 + threadIdx.x;
    const size_t total = (size_t)Bb * Nn_TOK * 768;
    if (idx >= total) return;
    int c = idx % 768;
    size_t r = idx / 768;
    int n = r % Nn_TOK, b = r / Nn_TOK;
    float v;
    if (n == 0) v = cls[c];
    else       v = pe[((size_t)b * 196 + (n - 1)) * 768 + c];
    t[idx] = v + pos[(size_t)n * 768 + c];
}

// ---------------- elementwise fp32 -> bf16 convert ----------------
__global__ void cvt_kernel(const float* __restrict__ src, ushort* __restrict__ dst, int n) {
    int idx = blockIdx.x * 256 + threadIdx.x;
    if (idx < n) dst[idx] = f2b(src[idx]);
}

// ---------------- tiled transpose-convert: src (K,N) fp32 -> dst (N,K) bf16 ----------------
__global__ __launch_bounds__(256) void transpose_one(const float* __restrict__ src,
                                                     ushort* __restrict__ dst, int K, int N) {
    int k0 = blockIdx.x * 32, n0 = blockIdx.y * 32;
    __shared__ float tile[32][33];
    int tx = threadIdx.x & 31, ty = threadIdx.x >> 5;
    #pragma unroll
    for (int r = ty; r < 32; r += 8)
        if (k0 + r < K && n0 + tx < N)
            tile[r][tx] = src[(size_t)(k0 + r) * N + n0 + tx];
    __syncthreads();
    #pragma unroll
    for (int r = ty; r < 32; r += 8)
        if (n0 + r < N && k0 + tx < K)
            dst[(size_t)(n0 + r) * K + k0 + tx] = f2b(tile[tx][r]);
}

// ---------------- per-layer 4-weight transpose-convert (dims all %32==0) ----------------
__global__ __launch_bounds__(256) void transpose4_kernel(
    const float* __restrict__ qkvw, const float* __restrict__ projw,
    const float* __restrict__ w1, const float* __restrict__ w2,
    ushort* __restrict__ dq, ushort* __restrict__ dp,
    ushort* __restrict__ d1, ushort* __restrict__ d2)
{
    int which = blockIdx.z;
    const float* src; ushort* dst; int K, N;
    if (which == 0)      { src = qkvw; dst = dq; K = 768;  N = 2304; }
    else if (which == 1) { src = projw; dst = dp; K = 768;  N = 768;  }
    else if (which == 2) { src = w1;   dst = d1; K = 768;  N = 3072; }
    else                 { src = w2;   dst = d2; K = 3072; N = 768;  }
    int k0 = blockIdx.x * 32, n0 = blockIdx.y * 32;
    if (k0 >= K || n0 >= N) return;
    __shared__ float tile[32][33];
    int tx = threadIdx.x & 31, ty = threadIdx.x >> 5;
    #pragma unroll
    for (int r = ty; r < 32; r += 8)
        tile[r][tx] = src[(size_t)(k0 + r) * N + n0 + tx];
    __syncthreads();
    #pragma unroll
    for (int r = ty; r < 32; r += 8)
        dst[(size_t)(n0 + r) * K + k0 + tx] = f2b(tile[tx][r]);
}

// ---------------- bf16 MFMA GEMM: A (M,K) bf16 @ B^T (N,K) bf16 -> out ----------------
// flags: 1 = exact gelu, 2 = bf16 output. K % 32 == 0 required.
#define TM 128
#define TN 128
__global__ __launch_bounds__(256) void gemm_bf16(
    const ushort* __restrict__ A, const ushort* __restrict__ B,
    void* __restrict__ outp, const float* __restrict__ bias,
    const float* __restrict__ residual, int M, int N, int K, int flags)
{
    // LDS layout [kseg h][row r][8 bf16] => granule (h*128+r) at linear offset *16B.
    __shared__ ushort As[4][128][8];
    __shared__ ushort Bs[4][128][8];
    const int tid = threadIdx.x;
    const int wave = tid >> 6, lane = tid & 63;
    const int br = blockIdx.y * TM, bc = blockIdx.x * TN;
    const int wm = (wave >> 1) * 64, wn = (wave & 1) * 64;

    // staging granules: g0 = tid (h in 0..1), g1 = tid+256 (h in 2..3)
    const int hA0 = tid >> 7, rA0 = tid & 127;
    const int hA1 = (tid + 256) >> 7, rA1 = tid & 127;
    const ushort* pA0 = A + (size_t)min(br + rA0, M - 1) * K + hA0 * 8;
    const ushort* pA1 = A + (size_t)min(br + rA1, M - 1) * K + hA1 * 8;
    const ushort* pB0 = B + (size_t)min(bc + rA0, N - 1) * K + hA0 * 8;
    const ushort* pB1 = B + (size_t)min(bc + rA1, N - 1) * K + hA1 * 8;
    ushort* sA0 = &As[0][0][0] + (size_t)(wave * 64) * 8;
    ushort* sA1 = &As[0][0][0] + (size_t)(256 + wave * 64) * 8;
    ushort* sB0 = &Bs[0][0][0] + (size_t)(wave * 64) * 8;
    ushort* sB1 = &Bs[0][0][0] + (size_t)(256 + wave * 64) * 8;

    f32x4 acc[4][4];
    #pragma unroll
    for (int i = 0; i < 4; ++i)
        #pragma unroll
        for (int j = 0; j < 4; ++j) acc[i][j] = (f32x4){0.f, 0.f, 0.f, 0.f};

    const int h = lane >> 4, m16 = lane & 15;
    const int nk = K >> 5;
    for (int kt = 0; kt < nk; ++kt) {
        __syncthreads();
        gld16(pA0, sA0); gld16(pA1, sA1);
        gld16(pB0, sB0); gld16(pB1, sB1);
        pA0 += 32; pA1 += 32; pB0 += 32; pB1 += 32;
        __syncthreads();
        short8 af[4], bfr[4];
        #pragma unroll
        for (int i = 0; i < 4; ++i) af[i]  = *(const short8*)&As[h][wm + i * 16 + m16][0];
        #pragma unroll
        for (int j = 0; j < 4; ++j) bfr[j] = *(const short8*)&Bs[h][wn + j * 16 + m16][0];
        #pragma unroll
        for (int i = 0; i < 4; ++i)
            #pragma unroll
            for (int j = 0; j < 4; ++j)
                acc[i][j] = __builtin_amdgcn_mfma_f32_16x16x32_bf16(af[i], bfr[j], acc[i][j], 0, 0, 0);
    }

    const bool obf = (flags & 2) != 0, gelu = (flags & 1) != 0;
    const int q = lane >> 4, cx = lane & 15;
    #pragma unroll
    for (int j = 0; j < 4; ++j) {
        int gc = bc + wn + j * 16 + cx;
        if (gc >= N) continue;
        float bv = bias ? bias[gc] : 0.f;
        #pragma unroll
        for (int i = 0; i < 4; ++i) {
            #pragma unroll
            for (int r = 0; r < 4; ++r) {
                int gr = br + wm + i * 16 + q * 4 + r;
                if (gr >= M) continue;
                float v = acc[i][j][r] + bv;
                if (gelu) v = 0.5f * v * (1.f + erff(v * 0.70710678118654752f));
                size_t off = (size_t)gr * N + gc;
                if (residual) v += residual[off];
                if (obf) ((ushort*)outp)[off] = f2b(v);
                else     ((float*)outp)[off] = v;
            }
        }
    }
}

// ---------------- LayerNorm: fp32 in -> bf16 out, rows x 768 ----------------
__global__ __launch_bounds__(256) void ln_kernel(
    const float* __restrict__ in, ushort* __restrict__ out,
    const float* __restrict__ w, const float* __restrict__ b, long in_stride)
{
    int row = blockIdx.x;
    const float* xr = in + (size_t)row * in_stride;
    ushort* orow = out + (size_t)row * 768;
    int tid = threadIdx.x;
    float vals[3];
    float s = 0.f, s2 = 0.f;
    #pragma unroll
    for (int l = 0; l < 3; ++l) {
        float v = xr[tid + l * 256];
        vals[l] = v; s += v; s2 += v * v;
    }
    __shared__ float sh[256];
    __shared__ float stats[2];
    sh[tid] = s; __syncthreads();
    for (int o = 128; o > 0; o >>= 1) { if (tid < o) sh[tid] += sh[tid + o]; __syncthreads(); }
    if (tid == 0) stats[0] = sh[0];
    __syncthreads();
    sh[tid] = s2; __syncthreads();
    for (int o = 128; o > 0; o >>= 1) { if (tid < o) sh[tid] += sh[tid + o]; __syncthreads(); }
    if (tid == 0) stats[1] = sh[0];
    __syncthreads();
    float mean = stats[0] * (1.f / 768.f);
    float var = stats[1] * (1.f / 768.f) - mean * mean;
    float rstd = rsqrtf(var + 1e-5f);
    #pragma unroll
    for (int l = 0; l < 3; ++l) {
        int c = tid + l * 256;
        orow[c] = f2b((vals[l] - mean) * rstd * w[c] + b[c]);
    }
}

// ---------------- Attention: block per (head, batch, qsplit); K/V in LDS ----------------
#define KVPAD 70
__global__ __launch_bounds__(256) void attn_kernel(
    const ushort* __restrict__ qkv, ushort* __restrict__ out)
{
    int h = blockIdx.x, b = blockIdx.y, zs = blockIdx.z;
    __shared__ ushort Ksh[Nn_TOK * KVPAD];
    __shared__ ushort Vsh[Nn_TOK * KVPAD];
    __shared__ float probs[4][256];
    int tid = threadIdx.x, wave = tid >> 6, lane = tid & 63;
    const size_t base = (size_t)b * Nn_TOK * 2304 + (size_t)h * 64;
    // cooperative K/V load (uint = 2 bf16)
    for (int idx = tid; idx < Nn_TOK * 32; idx += 256) {
        int n = idx >> 5, d2 = (idx & 31) * 2;
        const ushort* kp = qkv + base + 768 + (size_t)n * 2304 + d2;
        *(unsigned*)&Ksh[n * KVPAD + d2] = *(const unsigned*)kp;
        *(unsigned*)&Vsh[n * KVPAD + d2] = *(const unsigned*)(kp + 768);
    }
    __syncthreads();
    for (int qi = zs * 4 + wave; qi < Nn_TOK; qi += 8) {
        float qreg = b2f(qkv[base + (size_t)qi * 2304 + lane]);
        float sc[4] = {0.f, 0.f, 0.f, 0.f};
        int k0 = lane, k1 = lane + 64, k2 = lane + 128, k3 = min(lane + 192, Nn_TOK - 1);
        for (int d = 0; d < 64; d += 2) {
            float qd0 = __shfl(qreg, d);
            float qd1 = __shfl(qreg, d + 1);
            unsigned u0 = *(const unsigned*)&Ksh[k0 * KVPAD + d];
            unsigned u1 = *(const unsigned*)&Ksh[k1 * KVPAD + d];
            unsigned u2 = *(const unsigned*)&Ksh[k2 * KVPAD + d];
            unsigned u3 = *(const unsigned*)&Ksh[k3 * KVPAD + d];
            union { unsigned u; float f; } lo, hi;
            lo.u = u0 << 16; hi.u = u0 & 0xffff0000u; sc[0] += qd0 * lo.f + qd1 * hi.f;
            lo.u = u1 << 16; hi.u = u1 & 0xffff0000u; sc[1] += qd0 * lo.f + qd1 * hi.f;
            lo.u = u2 << 16; hi.u = u2 & 0xffff0000u; sc[2] += qd0 * lo.f + qd1 * hi.f;
            lo.u = u3 << 16; hi.u = u3 & 0xffff0000u; sc[3] += qd0 * lo.f + qd1 * hi.f;
        }
        float mx = -INFINITY;
        #pragma unroll
        for (int t2 = 0; t2 < 4; ++t2) {
            int k = lane + t2 * 64;
            bool valid = (k < Nn_TOK) && (qi == 0 || k == 0 ||
                (abs((qi - 1) / Gg - (k - 1) / Gg) <= 3 && abs((qi - 1) % Gg - (k - 1) % Gg) <= 3));
            sc[t2] = valid ? sc[t2] * 0.125f : -INFINITY;
            mx = fmaxf(mx, sc[t2]);
        }
        for (int o = 32; o > 0; o >>= 1) mx = fmaxf(mx, __shfl_xor(mx, o));
        float ls = 0.f;
        #pragma unroll
        for (int t2 = 0; t2 < 4; ++t2) {
            float e = expf(sc[t2] - mx);
            ls += e;
            probs[wave][lane + t2 * 64] = e;
        }
        for (int o = 32; o > 0; o >>= 1) ls += __shfl_xor(ls, o);
        float inv = 1.f / ls;
        float acc = 0.f;
        for (int k = 0; k < Nn_TOK; ++k)
            acc += probs[wave][k] * b2f(Vsh[k * KVPAD + lane]);
        out[((size_t)b * Nn_TOK + qi) * 768 + (size_t)h * 64 + lane] = f2b(acc * inv);
    }
}

extern "C" void kernel_launch(void* const* d_in, const int* in_sizes, int n_in,
                              void* d_out, int out_size, void* d_ws, size_t ws_size,
                              hipStream_t stream) {
    const float* x        = (const float*)d_in[0];
    const float* patch_w  = (const float*)d_in[1];
    const float* patch_b  = (const float*)d_in[2];
    const float* cls_tok  = (const float*)d_in[3];
    const float* pos_emb  = (const float*)d_in[4];
    const float* ln1_w    = (const float*)d_in[5];
    const float* ln1_b    = (const float*)d_in[6];
    const float* qkv_w    = (const float*)d_in[7];
    const float* proj_w   = (const float*)d_in[8];
    const float* proj_b   = (const float*)d_in[9];
    const float* ln2_w    = (const float*)d_in[10];
    const float* ln2_b    = (const float*)d_in[11];
    const float* mlp_w1   = (const float*)d_in[12];
    const float* mlp_b1   = (const float*)d_in[13];
    const float* mlp_w2   = (const float*)d_in[14];
    const float* mlp_b2   = (const float*)d_in[15];
    const float* norm_w   = (const float*)d_in[16];
    const float* norm_b   = (const float*)d_in[17];
    const float* head_w   = (const float*)d_in[18];
    const float* head_b   = (const float*)d_in[19];
    float* out = (float*)d_out;

    char* ws = (char*)d_ws;
    float*  t     = (float*)ws;                        // 6304x768 fp32
    float*  pbuf  = (float*)(ws + 19365888);           // 6272x768 fp32
    ushort* abuf  = (ushort*)(ws + 38633472);          // 6304x768 bf16
    ushort* qbuf  = (ushort*)(ws + 48316416);          // 6304x2304 bf16
    ushort* hbuf  = (ushort*)(ws + 77365248);          // 6304x3072 bf16
    ushort* wq    = (ushort*)(ws + 116097024);         // 2304x768
    ushort* wp    = wq + 1769472;                      // 768x768
    ushort* w1t   = wp + 589824;                       // 3072x768
    ushort* w2t   = w1t + 2359296;                     // 768x3072
    ushort* pwbuf = (ushort*)(ws + 130252800);         // 768x768
    ushort* hwbuf = (ushort*)(ws + 131432448);         // 1000x768

    const int M_tok = Bb * Nn_TOK;  // 6304

    // im2col -> abuf (bf16)
    {
        size_t total = (size_t)Bb * 196 * 768;
        im2col_kernel<<<dim3((total + 255) / 256), 256, 0, stream>>>(x, abuf);
    }
    // patch_w (768,768) is already (N,K): plain convert
    cvt_kernel<<<dim3((589824 + 255) / 256), 256, 0, stream>>>(patch_w, pwbuf, 589824);
    // head_w (768,1000) -> (1000,768) bf16
    transpose_one<<<dim3(24, 32), 256, 0, stream>>>(head_w, hwbuf, 768, NC);
    // patch GEMM: pbuf = abuf(6272x768) @ pwbuf^T  (+patch_b)
    gemm_bf16<<<dim3(6, 49), 256, 0, stream>>>(abuf, pwbuf, pbuf, patch_b, nullptr, Bb * 196, Cc, Cc, 0);
    // assemble t
    {
        size_t total = (size_t)M_tok * 768;
        assemble_kernel<<<dim3((total + 255) / 256), 256, 0, stream>>>(pbuf, cls_tok, pos_emb, t);
    }

    for (int i = 0; i < Dn; ++i) {
        // transposed bf16 weights for this layer
        transpose4_kernel<<<dim3(96, 96, 4), 256, 0, stream>>>(
            qkv_w + (size_t)i * Cc * 3 * Cc, proj_w + (size_t)i * Cc * Cc,
            mlp_w1 + (size_t)i * Cc * HID, mlp_w2 + (size_t)i * HID * Cc,
            wq, wp, w1t, w2t);
        // LN1: t -> abuf
        ln_kernel<<<dim3(M_tok), 256, 0, stream>>>(t, abuf, ln1_w + i * Cc, ln1_b + i * Cc, Cc);
        // qkv: qbuf = abuf @ qkv_w[i]   (bf16 out)
        gemm_bf16<<<dim3(18, 50), 256, 0, stream>>>(abuf, wq, qbuf, nullptr, nullptr, M_tok, 3 * Cc, Cc, 2);
        // attention: qbuf -> abuf (bf16)
        attn_kernel<<<dim3(NHh, Bb, 2), 256, 0, stream>>>(qbuf, abuf);
        // proj + bias + residual -> t (fp32)
        gemm_bf16<<<dim3(6, 50), 256, 0, stream>>>(abuf, wp, t, proj_b + i * Cc, t, M_tok, Cc, Cc, 0);
        // LN2: t -> abuf
        ln_kernel<<<dim3(M_tok), 256, 0, stream>>>(t, abuf, ln2_w + i * Cc, ln2_b + i * Cc, Cc);
        // mlp1 + bias + gelu -> hbuf (bf16)
        gemm_bf16<<<dim3(24, 50), 256, 0, stream>>>(abuf, w1t, hbuf, mlp_b1 + i * HID, nullptr, M_tok, HID, Cc, 3);
        // mlp2 + bias + residual -> t (fp32)
        gemm_bf16<<<dim3(6, 50), 256, 0, stream>>>(hbuf, w2t, t, mlp_b2 + i * Cc, t, M_tok, Cc, HID, 0);
    }

    // final LN on token 0 of each batch -> abuf rows 0..31
    ln_kernel<<<dim3(Bb), 256, 0, stream>>>(t, abuf, norm_w, norm_b, (long)Nn_TOK * Cc);
    // head: out = abuf(32x768) @ hwbuf^T + head_b
    gemm_bf16<<<dim3(8, 1), 256, 0, stream>>>(abuf, hwbuf, out, head_b, nullptr, Bb, NC, Cc, 0);
}

// Round 3
// 7309.519 us; speedup vs baseline: 5.3709x; 1.2528x over previous
//
#include <hip/hip_runtime.h>
#include <hip/hip_bf16.h>
#include <math.h>

#define Dn 12
#define Cc 768
#define NHh 12
#define HD 64
#define Gg 14
#define Nn_TOK 197
#define HID 3072
#define NC 1000
#define Bb 32

typedef __attribute__((ext_vector_type(8))) short short8;
typedef __attribute__((ext_vector_type(4))) float f32x4;

__device__ __forceinline__ ushort f2b(float v) {
    union { float f; unsigned u; } x; x.f = v;
    unsigned r = x.u + 0x7fff + ((x.u >> 16) & 1);
    return (ushort)(r >> 16);
}
__device__ __forceinline__ float b2f(ushort v) {
    union { unsigned u; float f; } x; x.u = ((unsigned)v) << 16; return x.f;
}
__device__ __forceinline__ void gld16(const void* g, void* s) {
    __builtin_amdgcn_global_load_lds(
        (const __attribute__((address_space(1))) void*)g,
        (__attribute__((address_space(3))) void*)s, 16, 0, 0);
}

// ---------------- im2col: x (B,3,224,224) fp32 -> xp (B,196,768) bf16 ----------------
__global__ void im2col_kernel(const float* __restrict__ x, ushort* __restrict__ xp) {
    size_t idx = (size_t)blockIdx.x * 256 + threadIdx.x;
    const size_t total = (size_t)Bb * 196 * 768;
    if (idx >= total) return;
    int j = idx % 768;
    size_t t0 = idx / 768;
    int g = t0 % 196;
    int b = t0 / 196;
    int ch = j / 256, rem = j % 256, pr = rem / 16, pc = rem % 16;
    int gr = g / Gg, gc = g % Gg;
    int row = gr * 16 + pr, col = gc * 16 + pc;
    xp[idx] = f2b(x[(((size_t)b * 3 + ch) * 224 + row) * 224 + col]);
}

// ---------------- assemble t = concat(cls, patches) + pos (fp32) ----------------
__global__ void assemble_kernel(const float* __restrict__ pe, const float* __restrict__ cls,
                                const float* __restrict__ pos, float* __restrict__ t) {
    size_t idx = (size_t)blockIdx.x * 256 + threadIdx.x;
    const size_t total = (size_t)Bb * Nn_TOK * 768;
    if (idx >= total) return;
    int c = idx % 768;
    size_t r = idx / 768;
    int n = r % Nn_TOK, b = r / Nn_TOK;
    float v;
    if (n == 0) v = cls[c];
    else       v = pe[((size_t)b * 196 + (n - 1)) * 768 + c];
    t[idx] = v + pos[(size_t)n * 768 + c];
}

// ---------------- elementwise fp32 -> bf16 convert ----------------
__global__ void cvt_kernel(const float* __restrict__ src, ushort* __restrict__ dst, int n) {
    int idx = blockIdx.x * 256 + threadIdx.x;
    if (idx < n) dst[idx] = f2b(src[idx]);
}

// ---------------- tiled transpose-convert: src (K,N) fp32 -> dst (N,K) bf16 ----------------
__global__ __launch_bounds__(256) void transpose_one(const float* __restrict__ src,
                                                     ushort* __restrict__ dst, int K, int N) {
    int k0 = blockIdx.x * 32, n0 = blockIdx.y * 32;
    __shared__ float tile[32][33];
    int tx = threadIdx.x & 31, ty = threadIdx.x >> 5;
    #pragma unroll
    for (int r = ty; r < 32; r += 8)
        if (k0 + r < K && n0 + tx < N)
            tile[r][tx] = src[(size_t)(k0 + r) * N + n0 + tx];
    __syncthreads();
    #pragma unroll
    for (int r = ty; r < 32; r += 8)
        if (n0 + r < N && k0 + tx < K)
            dst[(size_t)(n0 + r) * K + k0 + tx] = f2b(tile[tx][r]);
}

// ---------------- per-layer 4-weight transpose-convert, tight 1D grid ----------------
// tiles: qkv 24x72=1728, proj 24x24=576, w1 24x96=2304, w2 96x24=2304 -> 6912 total
__global__ __launch_bounds__(256) void transpose4_kernel(
    const float* __restrict__ qkvw, const float* __restrict__ projw,
    const float* __restrict__ w1, const float* __restrict__ w2,
    ushort* __restrict__ dq, ushort* __restrict__ dp,
    ushort* __restrict__ d1, ushort* __restrict__ d2)
{
    int tile = blockIdx.x;
    const float* src; ushort* dst; int N, kt, nt;
    if (tile < 1728)      { src = qkvw; dst = dq; N = 2304; kt = tile / 72; nt = tile % 72; }
    else if (tile < 2304) { tile -= 1728; src = projw; dst = dp; N = 768; kt = tile / 24; nt = tile % 24; }
    else if (tile < 4608) { tile -= 2304; src = w1; dst = d1; N = 3072; kt = tile / 96; nt = tile % 96; }
    else                  { tile -= 4608; src = w2; dst = d2; N = 768; kt = tile / 24; nt = tile % 24; }
    int K = (dst == d2) ? 3072 : 768;
    int k0 = kt * 32, n0 = nt * 32;
    __shared__ float tilebuf[32][33];
    int tx = threadIdx.x & 31, ty = threadIdx.x >> 5;
    #pragma unroll
    for (int r = ty; r < 32; r += 8)
        tilebuf[r][tx] = src[(size_t)(k0 + r) * N + n0 + tx];
    __syncthreads();
    #pragma unroll
    for (int r = ty; r < 32; r += 8)
        dst[(size_t)(n0 + r) * K + k0 + tx] = f2b(tilebuf[tx][r]);
}

// ---------------- bf16 MFMA GEMM: A (M,K) bf16 @ B^T (N,K) bf16 -> out ----------------
// flags: 1 = exact gelu, 2 = bf16 output. K % 32 == 0 required.
#define TM 128
#define TN 128
__global__ __launch_bounds__(256) void gemm_bf16(
    const ushort* __restrict__ A, const ushort* __restrict__ B,
    void* __restrict__ outp, const float* __restrict__ bias,
    const float* __restrict__ residual, int M, int N, int K, int flags)
{
    __shared__ ushort As[4][128][8];
    __shared__ ushort Bs[4][128][8];
    const int tid = threadIdx.x;
    const int wave = tid >> 6, lane = tid & 63;
    const int br = blockIdx.y * TM, bc = blockIdx.x * TN;
    const int wm = (wave >> 1) * 64, wn = (wave & 1) * 64;

    const int hA0 = tid >> 7, rA0 = tid & 127;
    const int hA1 = (tid + 256) >> 7;
    const ushort* pA0 = A + (size_t)min(br + rA0, M - 1) * K + hA0 * 8;
    const ushort* pA1 = A + (size_t)min(br + rA0, M - 1) * K + hA1 * 8;
    const ushort* pB0 = B + (size_t)min(bc + rA0, N - 1) * K + hA0 * 8;
    const ushort* pB1 = B + (size_t)min(bc + rA0, N - 1) * K + hA1 * 8;
    ushort* sA0 = &As[0][0][0] + (size_t)(wave * 64) * 8;
    ushort* sA1 = &As[0][0][0] + (size_t)(256 + wave * 64) * 8;
    ushort* sB0 = &Bs[0][0][0] + (size_t)(wave * 64) * 8;
    ushort* sB1 = &Bs[0][0][0] + (size_t)(256 + wave * 64) * 8;

    f32x4 acc[4][4];
    #pragma unroll
    for (int i = 0; i < 4; ++i)
        #pragma unroll
        for (int j = 0; j < 4; ++j) acc[i][j] = (f32x4){0.f, 0.f, 0.f, 0.f};

    const int h = lane >> 4, m16 = lane & 15;
    const int nk = K >> 5;
    for (int kt = 0; kt < nk; ++kt) {
        __syncthreads();
        gld16(pA0, sA0); gld16(pA1, sA1);
        gld16(pB0, sB0); gld16(pB1, sB1);
        pA0 += 32; pA1 += 32; pB0 += 32; pB1 += 32;
        __syncthreads();
        short8 af[4], bfr[4];
        #pragma unroll
        for (int i = 0; i < 4; ++i) af[i]  = *(const short8*)&As[h][wm + i * 16 + m16][0];
        #pragma unroll
        for (int j = 0; j < 4; ++j) bfr[j] = *(const short8*)&Bs[h][wn + j * 16 + m16][0];
        #pragma unroll
        for (int i = 0; i < 4; ++i)
            #pragma unroll
            for (int j = 0; j < 4; ++j)
                acc[i][j] = __builtin_amdgcn_mfma_f32_16x16x32_bf16(af[i], bfr[j], acc[i][j], 0, 0, 0);
    }

    const bool obf = (flags & 2) != 0, gelu = (flags & 1) != 0;
    const int q = lane >> 4, cx = lane & 15;
    #pragma unroll
    for (int j = 0; j < 4; ++j) {
        int gc = bc + wn + j * 16 + cx;
        if (gc >= N) continue;
        float bv = bias ? bias[gc] : 0.f;
        #pragma unroll
        for (int i = 0; i < 4; ++i) {
            #pragma unroll
            for (int r = 0; r < 4; ++r) {
                int gr = br + wm + i * 16 + q * 4 + r;
                if (gr >= M) continue;
                float v = acc[i][j][r] + bv;
                if (gelu) v = 0.5f * v * (1.f + erff(v * 0.70710678118654752f));
                size_t off = (size_t)gr * N + gc;
                if (residual) v += residual[off];
                if (obf) ((ushort*)outp)[off] = f2b(v);
                else     ((float*)outp)[off] = v;
            }
        }
    }
}

// ---------------- LayerNorm: fp32 in -> bf16 out, rows x 768 ----------------
__global__ __launch_bounds__(256) void ln_kernel(
    const float* __restrict__ in, ushort* __restrict__ out,
    const float* __restrict__ w, const float* __restrict__ b, long in_stride)
{
    int row = blockIdx.x;
    const float* xr = in + (size_t)row * in_stride;
    ushort* orow = out + (size_t)row * 768;
    int tid = threadIdx.x;
    float vals[3];
    float s = 0.f, s2 = 0.f;
    #pragma unroll
    for (int l = 0; l < 3; ++l) {
        float v = xr[tid + l * 256];
        vals[l] = v; s += v; s2 += v * v;
    }
    __shared__ float sh[256];
    __shared__ float stats[2];
    sh[tid] = s; __syncthreads();
    for (int o = 128; o > 0; o >>= 1) { if (tid < o) sh[tid] += sh[tid + o]; __syncthreads(); }
    if (tid == 0) stats[0] = sh[0];
    __syncthreads();
    sh[tid] = s2; __syncthreads();
    for (int o = 128; o > 0; o >>= 1) { if (tid < o) sh[tid] += sh[tid + o]; __syncthreads(); }
    if (tid == 0) stats[1] = sh[0];
    __syncthreads();
    float mean = stats[0] * (1.f / 768.f);
    float var = stats[1] * (1.f / 768.f) - mean * mean;
    float rstd = rsqrtf(var + 1e-5f);
    #pragma unroll
    for (int l = 0; l < 3; ++l) {
        int c = tid + l * 256;
        orow[c] = f2b((vals[l] - mean) * rstd * w[c] + b[c]);
    }
}

// ---------------- Attention, mask-sparse: block per (head, batch, qsplit) ----------------
// Non-cls query (r,c): valid keys = 7x7 window (<=49) + cls = <=50 of 197.
// lane l<49 -> window key (r-3+l/7, c-3+l%7); lane 49 -> cls. Dense path only for qi==0.
#define KVP 66
__global__ __launch_bounds__(256) void attn_kernel(
    const ushort* __restrict__ qkv, ushort* __restrict__ out)
{
    int h = blockIdx.x, b = blockIdx.y, zs = blockIdx.z;
    __shared__ ushort Ksh[Nn_TOK * KVP];
    __shared__ ushort Vsh[Nn_TOK * KVP];
    int tid = threadIdx.x, wave = tid >> 6, lane = tid & 63;
    const size_t base = (size_t)b * Nn_TOK * 2304 + (size_t)h * 64;
    for (int idx = tid; idx < Nn_TOK * 32; idx += 256) {
        int n = idx >> 5, d2 = (idx & 31) * 2;
        const ushort* kp = qkv + base + 768 + (size_t)n * 2304 + d2;
        *(unsigned*)&Ksh[n * KVP + d2] = *(const unsigned*)kp;
        *(unsigned*)&Vsh[n * KVP + d2] = *(const unsigned*)(kp + 768);
    }
    __syncthreads();
    for (int qi = zs * 4 + wave; qi < Nn_TOK; qi += 16) {
        float qreg = b2f(qkv[base + (size_t)qi * 2304 + lane]);
        if (qi == 0) {
            // cls query: dense over all 197 keys, 4 keys/lane
            float sc[4] = {0.f, 0.f, 0.f, 0.f};
            int kk[4];
            #pragma unroll
            for (int t = 0; t < 4; ++t) kk[t] = min(lane + t * 64, Nn_TOK - 1);
            for (int d = 0; d < 64; d += 2) {
                float qd0 = __shfl(qreg, d), qd1 = __shfl(qreg, d + 1);
                #pragma unroll
                for (int t = 0; t < 4; ++t) {
                    unsigned u = *(const unsigned*)&Ksh[kk[t] * KVP + d];
                    union { unsigned u; float f; } lo, hi;
                    lo.u = u << 16; hi.u = u & 0xffff0000u;
                    sc[t] += qd0 * lo.f + qd1 * hi.f;
                }
            }
            float mx = -INFINITY;
            #pragma unroll
            for (int t = 0; t < 4; ++t) {
                sc[t] = (lane + t * 64 < Nn_TOK) ? sc[t] * 0.125f : -INFINITY;
                mx = fmaxf(mx, sc[t]);
            }
            for (int o = 32; o > 0; o >>= 1) mx = fmaxf(mx, __shfl_xor(mx, o));
            float p[4]; float ls = 0.f;
            #pragma unroll
            for (int t = 0; t < 4; ++t) { p[t] = expf(sc[t] - mx); ls += p[t]; }
            for (int o = 32; o > 0; o >>= 1) ls += __shfl_xor(ls, o);
            float acc = 0.f;
            #pragma unroll
            for (int t = 0; t < 4; ++t) {
                int kmax = min(64, Nn_TOK - t * 64);
                for (int j = 0; j < kmax; ++j) {
                    float pj = __shfl(p[t], j);
                    acc += pj * b2f(Vsh[(t * 64 + j) * KVP + lane]);
                }
            }
            out[((size_t)b * Nn_TOK + qi) * 768 + (size_t)h * 64 + lane] = f2b(acc / ls);
        } else {
            int r = (qi - 1) / Gg, c = (qi - 1) % Gg;
            bool valid; int kid;
            if (lane < 49) {
                int rk = r + lane / 7 - 3, ck = c + lane % 7 - 3;
                valid = (rk >= 0 && rk < Gg && ck >= 0 && ck < Gg);
                kid = valid ? 1 + rk * Gg + ck : 0;
            } else if (lane == 49) { valid = true; kid = 0; }
            else { valid = false; kid = 0; }
            float sc = 0.f;
            for (int d = 0; d < 64; d += 2) {
                float qd0 = __shfl(qreg, d), qd1 = __shfl(qreg, d + 1);
                unsigned u = *(const unsigned*)&Ksh[kid * KVP + d];
                union { unsigned u; float f; } lo, hi;
                lo.u = u << 16; hi.u = u & 0xffff0000u;
                sc += qd0 * lo.f + qd1 * hi.f;
            }
            sc = valid ? sc * 0.125f : -INFINITY;
            float mx = sc;
            for (int o = 32; o > 0; o >>= 1) mx = fmaxf(mx, __shfl_xor(mx, o));
            float p = valid ? expf(sc - mx) : 0.f;
            float ls = p;
            for (int o = 32; o > 0; o >>= 1) ls += __shfl_xor(ls, o);
            float acc = 0.f;
            #pragma unroll 5
            for (int j = 0; j < 50; ++j) {
                float pj = __shfl(p, j);
                int kj = __shfl(kid, j);
                acc += pj * b2f(Vsh[kj * KVP + lane]);
            }
            out[((size_t)b * Nn_TOK + qi) * 768 + (size_t)h * 64 + lane] = f2b(acc / ls);
        }
    }
}

extern "C" void kernel_launch(void* const* d_in, const int* in_sizes, int n_in,
                              void* d_out, int out_size, void* d_ws, size_t ws_size,
                              hipStream_t stream) {
    const float* x        = (const float*)d_in[0];
    const float* patch_w  = (const float*)d_in[1];
    const float* patch_b  = (const float*)d_in[2];
    const float* cls_tok  = (const float*)d_in[3];
    const float* pos_emb  = (const float*)d_in[4];
    const float* ln1_w    = (const float*)d_in[5];
    const float* ln1_b    = (const float*)d_in[6];
    const float* qkv_w    = (const float*)d_in[7];
    const float* proj_w   = (const float*)d_in[8];
    const float* proj_b   = (const float*)d_in[9];
    const float* ln2_w    = (const float*)d_in[10];
    const float* ln2_b    = (const float*)d_in[11];
    const float* mlp_w1   = (const float*)d_in[12];
    const float* mlp_b1   = (const float*)d_in[13];
    const float* mlp_w2   = (const float*)d_in[14];
    const float* mlp_b2   = (const float*)d_in[15];
    const float* norm_w   = (const float*)d_in[16];
    const float* norm_b   = (const float*)d_in[17];
    const float* head_w   = (const float*)d_in[18];
    const float* head_b   = (const float*)d_in[19];
    float* out = (float*)d_out;

    char* ws = (char*)d_ws;
    float*  t     = (float*)ws;                        // 6304x768 fp32
    float*  pbuf  = (float*)(ws + 19365888);           // 6272x768 fp32
    ushort* abuf  = (ushort*)(ws + 38633472);          // 6304x768 bf16
    ushort* qbuf  = (ushort*)(ws + 48316416);          // 6304x2304 bf16
    ushort* hbuf  = (ushort*)(ws + 77365248);          // 6304x3072 bf16
    ushort* wq    = (ushort*)(ws + 116097024);         // 2304x768
    ushort* wp    = wq + 1769472;                      // 768x768
    ushort* w1t   = wp + 589824;                       // 3072x768
    ushort* w2t   = w1t + 2359296;                     // 768x3072
    ushort* pwbuf = (ushort*)(ws + 130252800);         // 768x768
    ushort* hwbuf = (ushort*)(ws + 131432448);         // 1000x768

    const int M_tok = Bb * Nn_TOK;  // 6304

    {
        size_t total = (size_t)Bb * 196 * 768;
        im2col_kernel<<<dim3((total + 255) / 256), 256, 0, stream>>>(x, abuf);
    }
    cvt_kernel<<<dim3((589824 + 255) / 256), 256, 0, stream>>>(patch_w, pwbuf, 589824);
    transpose_one<<<dim3(24, 32), 256, 0, stream>>>(head_w, hwbuf, 768, NC);
    gemm_bf16<<<dim3(6, 49), 256, 0, stream>>>(abuf, pwbuf, pbuf, patch_b, nullptr, Bb * 196, Cc, Cc, 0);
    {
        size_t total = (size_t)M_tok * 768;
        assemble_kernel<<<dim3((total + 255) / 256), 256, 0, stream>>>(pbuf, cls_tok, pos_emb, t);
    }

    for (int i = 0; i < Dn; ++i) {
        transpose4_kernel<<<dim3(6912), 256, 0, stream>>>(
            qkv_w + (size_t)i * Cc * 3 * Cc, proj_w + (size_t)i * Cc * Cc,
            mlp_w1 + (size_t)i * Cc * HID, mlp_w2 + (size_t)i * HID * Cc,
            wq, wp, w1t, w2t);
        ln_kernel<<<dim3(M_tok), 256, 0, stream>>>(t, abuf, ln1_w + i * Cc, ln1_b + i * Cc, Cc);
        gemm_bf16<<<dim3(18, 50), 256, 0, stream>>>(abuf, wq, qbuf, nullptr, nullptr, M_tok, 3 * Cc, Cc, 2);
        attn_kernel<<<dim3(NHh, Bb, 4), 256, 0, stream>>>(qbuf, abuf);
        gemm_bf16<<<dim3(6, 50), 256, 0, stream>>>(abuf, wp, t, proj_b + i * Cc, t, M_tok, Cc, Cc, 0);
        ln_kernel<<<dim3(M_tok), 256, 0, stream>>>(t, abuf, ln2_w + i * Cc, ln2_b + i * Cc, Cc);
        gemm_bf16<<<dim3(24, 50), 256, 0, stream>>>(abuf, w1t, hbuf, mlp_b1 + i * HID, nullptr, M_tok, HID, Cc, 3);
        gemm_bf16<<<dim3(6, 50), 256, 0, stream>>>(hbuf, w2t, t, mlp_b2 + i * Cc, t, M_tok, Cc, HID, 0);
    }

    ln_kernel<<<dim3(Bb), 256, 0, stream>>>(t, abuf, norm_w, norm_b, (long)Nn_TOK * Cc);
    gemm_bf16<<<dim3(8, 1), 256, 0, stream>>>(abuf, hwbuf, out, head_b, nullptr, Bb, NC, Cc, 0);
}